// Round 9
// baseline (38.457 us; speedup 1.0000x reference)
//
#include <hip/hip_runtime.h>

#define NCLUSTER 512
#define NC 3
#define HW 65536
#define BLOCK 256
#define NW 4                     // waves per block = cluster subsets
#define KSUB (NCLUSTER / NW)     // 128 clusters per wave
#define PPT 4                    // pixels per thread (256 px per block)
#define EPS 1e-4f                // >> 2*delta (delta <= ~1.5e-5 for |t|<=70)

// Certified-exact fp32 path: argmin_k d_k == argmin_k t_k,
// t_k = 0.5*||C_k||^2 - x.C_k; exact global top-2 certifies the fp32 argmin
// when gap >= EPS; near-ties are queue-compacted and resolved in exact fp64
// (validated absmax 0, R1/R8). NEW in R9: the main K-loop reads NO memory —
// each wave holds its 128 clusters in per-lane VGPRs (2 float4) and
// broadcasts cluster j via v_readlane (VALU pipe). R1-R8 showed the uniform
// LDS-broadcast path costs ~2x its issue model and resists pipelining;
// readlane makes the loop pure VALU-issue-bound, which 4 waves/SIMD saturates.
#define RL(v, j) __uint_as_float(__builtin_amdgcn_readlane(__float_as_uint(v), (j)))

__global__ __launch_bounds__(BLOCK) void kmeans_assign(
    const float* __restrict__ x,   // [4,3,256,256]
    const float* __restrict__ C,   // [512,3]
    int* __restrict__ out)         // [4,65536]
{
    __shared__ float4 lc[NCLUSTER];        // {c0,c1,c2, 0.5*||c||^2}  8 KB
    __shared__ float  rb1[NW][BLOCK];      // per-subset best1          4 KB
    __shared__ float  rb2[NW][BLOCK];      // per-subset exact 2nd-best 4 KB
    __shared__ int    ridx[NW][BLOCK];     // per-subset argmin         4 KB
    __shared__ int    qpx[BLOCK];          // near-tie pixel queue      1 KB
    __shared__ int    qcnt;

    if (threadIdx.x == 0) qcnt = 0;
    for (int k = threadIdx.x; k < NCLUSTER; k += BLOCK) {
        double c0 = C[k * NC + 0];
        double c1 = C[k * NC + 1];
        double c2 = C[k * NC + 2];
        lc[k] = make_float4((float)c0, (float)c1, (float)c2,
                            (float)(0.5 * (c0 * c0 + c1 * c1 + c2 * c2)));
    }
    __syncthreads();

    const int w = threadIdx.x >> 6;        // wave id = cluster subset
    const int l = threadIdx.x & 63;        // lane
    const int B0 = blockIdx.x * BLOCK;     // first global pixel of block
    const int pB = B0 & (HW - 1);          // pixel base within batch
    const float* xb = x + (size_t)(B0 >> 16) * NC * HW;

    const int k0 = w * KSUB;
    // Wave w's 128 clusters, register-resident: lane l holds k0+l and k0+64+l.
    float4 g0 = lc[k0 + l];
    float4 g1 = lc[k0 + 64 + l];

    float x0[PPT], x1[PPT], x2[PPT], b1[PPT], b2[PPT];
    int id[PPT];
#pragma unroll
    for (int i = 0; i < PPT; ++i) {
        int p = pB + l + i * 64;
        x0[i] = xb[p];
        x1[i] = xb[p + HW];
        x2[i] = xb[p + 2 * HW];
        b1[i] = 1e30f;
        b2[i] = 1e30f;
        id[i] = 0;
    }

#pragma unroll
    for (int h = 0; h < 2; ++h) {
        const float4 G = h ? g1 : g0;
        const int kb = k0 + h * 64;
#pragma unroll 8
        for (int j = 0; j < 64; ++j) {
            // Broadcast cluster kb+j from lane j: 4 readlanes, zero memory.
            float c0 = RL(G.x, j);
            float c1 = RL(G.y, j);
            float c2 = RL(G.z, j);
            float cw = RL(G.w, j);
#pragma unroll
            for (int i = 0; i < PPT; ++i) {
                float t = cw;
                t = __builtin_fmaf(-x0[i], c0, t);
                t = __builtin_fmaf(-x1[i], c1, t);
                t = __builtin_fmaf(-x2[i], c2, t);
                bool lt = t < b1[i];                              // strict: first k wins
                b2[i] = __builtin_amdgcn_fmed3f(t, b1[i], b2[i]); // exact 2nd-best
                id[i] = lt ? (kb + j) : id[i];
                b1[i] = fminf(t, b1[i]);
            }
        }
    }

#pragma unroll
    for (int i = 0; i < PPT; ++i) {
        rb1[w][l + i * 64] = b1[i];
        rb2[w][l + i * 64] = b2[i];
        ridx[w][l + i * 64] = id[i];
    }
    __syncthreads();

    // Merge subsets for pixel t (one px per thread), w ascending so the
    // lowest cluster index wins on equal fp32 scores (argmin semantics).
    {
        const int t = threadIdx.x;
        float g1m = rb1[0][t];
        float g2m = rb2[0][t];
        int gi = ridx[0][t];
#pragma unroll
        for (int ww = 1; ww < NW; ++ww) {
            float a1 = rb1[ww][t];
            float a2 = rb2[ww][t];
            int ai = ridx[ww][t];
            bool lt = a1 < g1m;
            g2m = lt ? fminf(g1m, a2) : fminf(g2m, a1);   // exact global 2nd-best
            gi = lt ? ai : gi;
            g1m = fminf(g1m, a1);
        }
        if (g2m - g1m < EPS) {
            qpx[atomicAdd(&qcnt, 1)] = t;   // near-tie: defer to exact resolve
        } else {
            out[B0 + t] = gi;               // certified correct
        }
    }
    __syncthreads();

    // Wave-cooperative exact resolve: one queued pixel per wave at a time,
    // 64 lanes x 8 clusters, exact fp64 direct distances (validated absmax 0),
    // smallest-k tie-break.
    const int n = qcnt;
    for (int e = w; e < n; e += NW) {
        const int t = qpx[e];
        const int p = pB + t;
        double X0 = (double)xb[p];
        double X1 = (double)xb[p + HW];
        double X2 = (double)xb[p + 2 * HW];
        double bd = 1e300;
        int bi = 0;
#pragma unroll
        for (int j = 0; j < NCLUSTER / 64; ++j) {
            int k = j * 64 + l;              // ascending per lane
            float4 c = lc[k];
            double d0 = X0 - (double)c.x;
            double d1 = X1 - (double)c.y;
            double d2 = X2 - (double)c.z;
            double d = d0 * d0 + d1 * d1 + d2 * d2;
            if (d < bd) { bd = d; bi = k; }  // strict: smallest k in lane wins
        }
#pragma unroll
        for (int m = 1; m < 64; m <<= 1) {   // butterfly argmin reduce
            double od = __shfl_xor(bd, m, 64);
            int oi = __shfl_xor(bi, m, 64);
            bool take = (od < bd) || (od == bd && oi < bi);
            bd = take ? od : bd;
            bi = take ? oi : bi;
        }
        if (l == 0) out[B0 + t] = bi;
    }
}

extern "C" void kernel_launch(void* const* d_in, const int* in_sizes, int n_in,
                              void* d_out, int out_size, void* d_ws, size_t ws_size,
                              hipStream_t stream) {
    const float* x = (const float*)d_in[0];
    const float* C = (const float*)d_in[1];
    int* out = (int*)d_out;

    int total = out_size;              // 262144
    int grid = total / BLOCK;          // 1024 blocks -> 16 waves/CU, 4/SIMD
    kmeans_assign<<<grid, BLOCK, 0, stream>>>(x, C, out);
}

// Round 10
// 33.479 us; speedup vs baseline: 1.1487x; 1.1487x over previous
//
#include <hip/hip_runtime.h>

#define NCLUSTER 512
#define NC 3
#define HW 65536
#define BLOCK 256
#define NW 4                     // waves per block = cluster subsets
#define KSUB (NCLUSTER / NW)     // 128 clusters per wave
#define PPT 2                    // pixels per thread
#define PXB (64 * PPT)           // pixels per block = 128
#define EPS 1e-4f                // >> 2*delta (delta <= ~3e-5 for |t|<=~100)

// Certified-exact fp32 path: argmin_k d_k == argmin_k t_k,
// t_k = 0.5*||C_k||^2 - x.C_k; exact global top-2 certifies the fp32 argmin
// when gap >= EPS; near-ties are queue-compacted and resolved exactly in
// fp64 (validated absmax 0, R1/R8/R9). R10 change: PPT 4->2, grid 1024->2048
// -> 8 blocks/CU, 32 waves/CU = 8 waves/SIMD (HW max). R1-R9 showed TLP is
// the only latency-hiding that works here (readlane and manual pipelining
// both lost to the plain LDS-broadcast loop); this doubles it at constant
// per-SIMD VALU work.
__global__ __launch_bounds__(BLOCK) void kmeans_assign(
    const float* __restrict__ x,   // [4,3,256,256]
    const float* __restrict__ C,   // [512,3]
    int* __restrict__ out)         // [4,65536]
{
    __shared__ float4 lc[NCLUSTER];      // {c0,c1,c2, 0.5*||c||^2}  8 KB
    __shared__ float  rb1[NW][PXB];      // per-subset best1          2 KB
    __shared__ float  rb2[NW][PXB];      // per-subset exact 2nd-best 2 KB
    __shared__ int    ridx[NW][PXB];     // per-subset argmin         2 KB
    __shared__ int    qpx[PXB];          // near-tie pixel queue      0.5 KB
    __shared__ int    qcnt;

    if (threadIdx.x == 0) qcnt = 0;
    for (int k = threadIdx.x; k < NCLUSTER; k += BLOCK) {
        double c0 = C[k * NC + 0];
        double c1 = C[k * NC + 1];
        double c2 = C[k * NC + 2];
        lc[k] = make_float4((float)c0, (float)c1, (float)c2,
                            (float)(0.5 * (c0 * c0 + c1 * c1 + c2 * c2)));
    }
    __syncthreads();

    const int w = threadIdx.x >> 6;        // wave id = cluster subset
    const int l = threadIdx.x & 63;        // lane
    const int B0 = blockIdx.x * PXB;       // first global pixel of block
    const int pB = B0 & (HW - 1);          // pixel base within batch
    const float* xb = x + (size_t)(B0 >> 16) * NC * HW;

    float x0[PPT], x1[PPT], x2[PPT], b1[PPT], b2[PPT];
    int id[PPT];
#pragma unroll
    for (int i = 0; i < PPT; ++i) {
        int p = pB + l + i * 64;
        x0[i] = xb[p];
        x1[i] = xb[p + HW];
        x2[i] = xb[p + 2 * HW];
        b1[i] = 1e30f;
        b2[i] = 1e30f;
        id[i] = 0;
    }

    const int k0 = w * KSUB;
#pragma unroll 4
    for (int k = 0; k < KSUB; ++k) {
        float4 c = lc[k0 + k];   // one uniform ds_read_b128, 14 VALU ops follow
#pragma unroll
        for (int i = 0; i < PPT; ++i) {
            float t = __builtin_fmaf(-x0[i], c.x, c.w);       // all-VGPR, no mov
            t = __builtin_fmaf(-x1[i], c.y, t);
            t = __builtin_fmaf(-x2[i], c.z, t);
            bool lt = t < b1[i];                              // strict: first k wins
            b2[i] = __builtin_amdgcn_fmed3f(t, b1[i], b2[i]); // exact 2nd-best
            id[i] = lt ? (k0 + k) : id[i];
            b1[i] = fminf(t, b1[i]);
        }
    }

#pragma unroll
    for (int i = 0; i < PPT; ++i) {
        rb1[w][l + i * 64] = b1[i];
        rb2[w][l + i * 64] = b2[i];
        ridx[w][l + i * 64] = id[i];
    }
    __syncthreads();

    // Merge subsets for pixel t (threads 0..PXB-1), w ascending so the
    // lowest cluster index wins on equal fp32 scores (argmin semantics).
    if (threadIdx.x < PXB) {
        const int t = threadIdx.x;
        float g1m = rb1[0][t];
        float g2m = rb2[0][t];
        int gi = ridx[0][t];
#pragma unroll
        for (int ww = 1; ww < NW; ++ww) {
            float a1 = rb1[ww][t];
            float a2 = rb2[ww][t];
            int ai = ridx[ww][t];
            bool lt = a1 < g1m;
            g2m = lt ? fminf(g1m, a2) : fminf(g2m, a1);   // exact global 2nd-best
            gi = lt ? ai : gi;
            g1m = fminf(g1m, a1);
        }
        if (g2m - g1m < EPS) {
            qpx[atomicAdd(&qcnt, 1)] = t;   // near-tie: defer to exact resolve
        } else {
            out[B0 + t] = gi;               // certified correct
        }
    }
    __syncthreads();

    // Wave-cooperative exact resolve: one queued pixel per wave at a time,
    // 64 lanes x 8 clusters, exact fp64 direct distances (validated absmax 0),
    // smallest-k tie-break.
    const int n = qcnt;
    for (int e = w; e < n; e += NW) {
        const int t = qpx[e];
        const int p = pB + t;
        double X0 = (double)xb[p];
        double X1 = (double)xb[p + HW];
        double X2 = (double)xb[p + 2 * HW];
        double bd = 1e300;
        int bi = 0;
#pragma unroll
        for (int j = 0; j < NCLUSTER / 64; ++j) {
            int k = j * 64 + l;              // ascending per lane
            float4 c = lc[k];
            double d0 = X0 - (double)c.x;
            double d1 = X1 - (double)c.y;
            double d2 = X2 - (double)c.z;
            double d = d0 * d0 + d1 * d1 + d2 * d2;
            if (d < bd) { bd = d; bi = k; }  // strict: smallest k in lane wins
        }
#pragma unroll
        for (int m = 1; m < 64; m <<= 1) {   // butterfly argmin reduce
            double od = __shfl_xor(bd, m, 64);
            int oi = __shfl_xor(bi, m, 64);
            bool take = (od < bd) || (od == bd && oi < bi);
            bd = take ? od : bd;
            bi = take ? oi : bi;
        }
        if (l == 0) out[B0 + t] = bi;
    }
}

extern "C" void kernel_launch(void* const* d_in, const int* in_sizes, int n_in,
                              void* d_out, int out_size, void* d_ws, size_t ws_size,
                              hipStream_t stream) {
    const float* x = (const float*)d_in[0];
    const float* C = (const float*)d_in[1];
    int* out = (int*)d_out;

    int total = out_size;              // 262144
    int grid = total / PXB;            // 2048 blocks -> 32 waves/CU, 8/SIMD
    kmeans_assign<<<grid, BLOCK, 0, stream>>>(x, C, out);
}